// Round 22
// baseline (90.075 us; speedup 1.0000x reference)
//
#include <hip/hip_runtime.h>
#include <hip/hip_bf16.h>
#include <math.h>

// y[b,i] = sum_j x[b,j] * r[(j-i) mod N] + bias[i]
//        = circular conv: y = IFFT(FFT(x) * FFT(c)) + bias, c[k] = r[(-k) mod N]
// Radix-16 FFT (N=4096 = 16^3), fp32, in-LDS, two rows packed per FFT.
//   R16 skeleton (5 passes, direct-global ends, pk-asm VOP3P math, PAD LDS,
//   launch_bounds(256,2)) with ONE change vs R16:
//   - the two MIDDLE __syncthreads (F16->F1, I1->I16) are replaced by a BARE
//     wave-local lgkmcnt(0) fence (NO sched_barrier pins - R17's mistake).
//     Proof: those exchanges touch only aligned 16-thread groups (same wave).

#define NFFT 4096
#define PAD(i) ((i) + ((i) >> 4))

typedef __attribute__((ext_vector_type(2))) float v2f;
typedef __attribute__((ext_vector_type(4))) float f32x4;
typedef __attribute__((ext_vector_type(4))) unsigned short us4;

#define RQ 0.70710678118654752f
#define C1 0.9238795325112867f
#define S1 0.3826834323650898f

// bare wave-local LDS fence: compiler memory barrier + HW wait for this
// wave's LDS ops. Valid ONLY for intra-wave producer/consumer pairs.
#define WAVE_FENCE() asm volatile("s_waitcnt lgkmcnt(0)" ::: "memory")

// ---- VOP3P packed-fp32 primitives (HW-verified R14/R15/R16) ----
__device__ __forceinline__ v2f padd(v2f a, v2f b) {
  v2f r;
  asm("v_pk_add_f32 %0, %1, %2" : "=v"(r) : "v"(a), "v"(b));
  return r;
}
__device__ __forceinline__ v2f psub(v2f a, v2f b) {
  v2f r;
  asm("v_pk_add_f32 %0, %1, %2 neg_lo:[0,1] neg_hi:[0,1]"
      : "=v"(r) : "v"(a), "v"(b));
  return r;
}
// a + (-i)*b = {a.x + b.y, a.y - b.x}
__device__ __forceinline__ v2f addmni(v2f a, v2f b) {
  v2f r;
  asm("v_pk_add_f32 %0, %1, %2 op_sel:[0,1] op_sel_hi:[1,0] neg_hi:[0,1]"
      : "=v"(r) : "v"(a), "v"(b));
  return r;
}
// a + (+i)*b = {a.x - b.y, a.y + b.x}
__device__ __forceinline__ v2f addmpi(v2f a, v2f b) {
  v2f r;
  asm("v_pk_add_f32 %0, %1, %2 op_sel:[0,1] op_sel_hi:[1,0] neg_lo:[0,1]"
      : "=v"(r) : "v"(a), "v"(b));
  return r;
}
// complex a*b
__device__ __forceinline__ v2f cmul(v2f a, v2f b) {
  v2f t, r;
  asm("v_pk_mul_f32 %0, %1, %2 op_sel:[0,0] op_sel_hi:[0,1]"
      : "=v"(t) : "v"(a), "v"(b));
  asm("v_pk_fma_f32 %0, %1, %2, %3 op_sel:[1,1,0] op_sel_hi:[1,0,1] neg_lo:[1,0,0]"
      : "=v"(r) : "v"(a), "v"(b), "v"(t));
  return r;
}
// complex a*conj(b)
__device__ __forceinline__ v2f cmulj(v2f a, v2f b) {
  v2f t, r;
  asm("v_pk_mul_f32 %0, %1, %2 op_sel:[0,0] op_sel_hi:[1,0]"
      : "=v"(t) : "v"(a), "v"(b));
  asm("v_pk_fma_f32 %0, %1, %2, %3 op_sel:[1,1,0] op_sel_hi:[0,1,1] neg_hi:[1,0,0]"
      : "=v"(r) : "v"(a), "v"(b), "v"(t));
  return r;
}

// ---- 4-point DFT building blocks (in-place, by reference) ----
__device__ __forceinline__ void fft4(v2f& x0, v2f& x1, v2f& x2, v2f& x3) {
  v2f t0 = padd(x0, x2), t1 = psub(x0, x2);
  v2f t2 = padd(x1, x3), t3 = psub(x1, x3);
  x0 = padd(t0, t2); x1 = addmni(t1, t3);
  x2 = psub(t0, t2); x3 = addmpi(t1, t3);
}
__device__ __forceinline__ void ifft4(v2f& x0, v2f& x1, v2f& x2, v2f& x3) {
  v2f t0 = padd(x0, x2), t1 = psub(x0, x2);
  v2f t2 = padd(x1, x3), t3 = psub(x1, x3);
  x0 = padd(t0, t2); x1 = addmpi(t1, t3);
  x2 = psub(t0, t2); x3 = addmni(t1, t3);
}

// ---- natural-order 16-point DFT (HW-verified R16) ----
__device__ __forceinline__ void fft16(v2f a[16]) {
  fft4(a[0], a[4], a[8], a[12]);
  fft4(a[1], a[5], a[9], a[13]);
  fft4(a[2], a[6], a[10], a[14]);
  fft4(a[3], a[7], a[11], a[15]);
  const v2f W1 = {C1, -S1}, W2 = {RQ, -RQ}, W3 = {S1, -C1};
  const v2f W6 = {-RQ, -RQ}, W9 = {-C1, S1};
  a[5] = cmul(a[5], W1);  a[9] = cmul(a[9], W2);   a[13] = cmul(a[13], W3);
  a[6] = cmul(a[6], W2);  /* a[10]: *(-i) folded */ a[14] = cmul(a[14], W6);
  a[7] = cmul(a[7], W3);  a[11] = cmul(a[11], W6); a[15] = cmul(a[15], W9);
  v2f x[16];
  {
    v2f t0 = padd(a[0], a[2]), t1 = psub(a[0], a[2]);
    v2f t2 = padd(a[1], a[3]), t3 = psub(a[1], a[3]);
    x[0] = padd(t0, t2); x[4] = addmni(t1, t3);
    x[8] = psub(t0, t2); x[12] = addmpi(t1, t3);
  }
  {
    v2f t0 = padd(a[4], a[6]), t1 = psub(a[4], a[6]);
    v2f t2 = padd(a[5], a[7]), t3 = psub(a[5], a[7]);
    x[1] = padd(t0, t2); x[5] = addmni(t1, t3);
    x[9] = psub(t0, t2); x[13] = addmpi(t1, t3);
  }
  {
    v2f t0 = addmni(a[8], a[10]), t1 = addmpi(a[8], a[10]);
    v2f t2 = padd(a[9], a[11]), t3 = psub(a[9], a[11]);
    x[2] = padd(t0, t2); x[6] = addmni(t1, t3);
    x[10] = psub(t0, t2); x[14] = addmpi(t1, t3);
  }
  {
    v2f t0 = padd(a[12], a[14]), t1 = psub(a[12], a[14]);
    v2f t2 = padd(a[13], a[15]), t3 = psub(a[13], a[15]);
    x[3] = padd(t0, t2); x[7] = addmni(t1, t3);
    x[11] = psub(t0, t2); x[15] = addmpi(t1, t3);
  }
#pragma unroll
  for (int q = 0; q < 16; ++q) a[q] = x[q];
}

__device__ __forceinline__ void ifft16(v2f a[16]) {
  ifft4(a[0], a[4], a[8], a[12]);
  ifft4(a[1], a[5], a[9], a[13]);
  ifft4(a[2], a[6], a[10], a[14]);
  ifft4(a[3], a[7], a[11], a[15]);
  const v2f W1 = {C1, -S1}, W2 = {RQ, -RQ}, W3 = {S1, -C1};
  const v2f W6 = {-RQ, -RQ}, W9 = {-C1, S1};
  a[5] = cmulj(a[5], W1);  a[9] = cmulj(a[9], W2);   a[13] = cmulj(a[13], W3);
  a[6] = cmulj(a[6], W2);  /* a[10]: *(+i) folded */  a[14] = cmulj(a[14], W6);
  a[7] = cmulj(a[7], W3);  a[11] = cmulj(a[11], W6); a[15] = cmulj(a[15], W9);
  v2f x[16];
  {
    v2f t0 = padd(a[0], a[2]), t1 = psub(a[0], a[2]);
    v2f t2 = padd(a[1], a[3]), t3 = psub(a[1], a[3]);
    x[0] = padd(t0, t2); x[4] = addmpi(t1, t3);
    x[8] = psub(t0, t2); x[12] = addmni(t1, t3);
  }
  {
    v2f t0 = padd(a[4], a[6]), t1 = psub(a[4], a[6]);
    v2f t2 = padd(a[5], a[7]), t3 = psub(a[5], a[7]);
    x[1] = padd(t0, t2); x[5] = addmpi(t1, t3);
    x[9] = psub(t0, t2); x[13] = addmni(t1, t3);
  }
  {
    v2f t0 = addmpi(a[8], a[10]), t1 = addmni(a[8], a[10]);
    v2f t2 = padd(a[9], a[11]), t3 = psub(a[9], a[11]);
    x[2] = padd(t0, t2); x[6] = addmpi(t1, t3);
    x[10] = psub(t0, t2); x[14] = addmni(t1, t3);
  }
  {
    v2f t0 = padd(a[12], a[14]), t1 = psub(a[12], a[14]);
    v2f t2 = padd(a[13], a[15]), t3 = psub(a[13], a[15]);
    x[3] = padd(t0, t2); x[7] = addmpi(t1, t3);
    x[11] = psub(t0, t2); x[15] = addmni(t1, t3);
  }
#pragma unroll
  for (int q = 0; q < 16; ++q) a[q] = x[q];
}

// apply a[q] *= b^q (CONJ: *= conj(b^q)); tree powers
template <bool CONJ>
__device__ __forceinline__ void tw_pow16(v2f a[16], v2f b) {
  const v2f p2 = cmul(b, b);
  const v2f p3 = cmul(p2, b);
  const v2f p4 = cmul(p2, p2);
  const v2f p5 = cmul(p4, b);
  const v2f p6 = cmul(p4, p2);
  const v2f p7 = cmul(p4, p3);
  const v2f p8 = cmul(p4, p4);
#define APQ(q, p)                         \
  if constexpr (CONJ) a[q] = cmulj(a[q], p); \
  else a[q] = cmul(a[q], p)
  APQ(1, b); APQ(2, p2); APQ(3, p3); APQ(4, p4);
  APQ(5, p5); APQ(6, p6); APQ(7, p7); APQ(8, p8);
  APQ(9, cmul(p8, b)); APQ(10, cmul(p8, p2)); APQ(11, cmul(p8, p3));
  APQ(12, cmul(p8, p4)); APQ(13, cmul(p8, p5)); APQ(14, cmul(p8, p6));
  APQ(15, cmul(p8, p7));
#undef APQ
}

// ---------------- kernel 0: twiddle table tw[j] = e^{-2pi i j/N} ----------------
__global__ __launch_bounds__(256) void build_tw(v2f* __restrict__ twg) {
  const int j = blockIdx.x * 256 + threadIdx.x;
  if (j < NFFT) {
    double ang = (-2.0 * 3.14159265358979323846) * (double)j / (double)NFFT;
    twg[j] = (v2f){(float)cos(ang), (float)sin(ang)};
  }
}

// ---- kernel 1: CgT[q*256+t] = (fwd chain of c at slot q of thread t)/N ----
__global__ __launch_bounds__(256, 2) void build_C(const float* __restrict__ r,
                                                  const v2f* __restrict__ twg,
                                                  v2f* __restrict__ CgT) {
  __shared__ v2f d[PAD(NFFT - 1) + 1];
  const int t = threadIdx.x;
  v2f a[16];
#pragma unroll
  for (int q = 0; q < 16; ++q) {
    const int idx = t + 256 * q;
    a[q] = (v2f){r[(NFFT - idx) & (NFFT - 1)], 0.f};
  }
  fft16(a);
  tw_pow16<false>(a, twg[t]);
#pragma unroll
  for (int q = 0; q < 16; ++q) d[PAD(t + 256 * q)] = a[q];
  __syncthreads();
  const int b16 = (t >> 4) * 256 + (t & 15);
#pragma unroll
  for (int q = 0; q < 16; ++q) a[q] = d[PAD(b16 + 16 * q)];
  fft16(a);
  tw_pow16<false>(a, twg[(t & 15) * 16]);
#pragma unroll
  for (int q = 0; q < 16; ++q) d[PAD(b16 + 16 * q)] = a[q];
  __syncthreads();
#pragma unroll
  for (int q = 0; q < 16; ++q) a[q] = d[PAD(16 * t + q)];
  fft16(a);
  const float s = 1.0f / (float)NFFT;
#pragma unroll
  for (int q = 0; q < 16; ++q)
    CgT[q * 256 + t] = (v2f){a[q].x * s, a[q].y * s};
}

// ------ kernel 2: packed 2-row radix-16 FFT conv, 2 barriers + 2 fences ------
__global__ __launch_bounds__(256, 2) void fft_conv15(
    const float* __restrict__ x, const v2f* __restrict__ CgT,
    const v2f* __restrict__ twg, const float* __restrict__ bias,
    float* __restrict__ y) {
  __shared__ v2f d[PAD(NFFT - 1) + 1];
  const int t = threadIdx.x;  // 0..255
  const size_t r0 = 2 * (size_t)blockIdx.x;
  const float* x0 = x + r0 * NFFT;
  const float* x1 = x0 + NFFT;
  float* y0 = y + r0 * NFFT;
  float* y1 = y0 + NFFT;

  v2f a[16];

  // ---- F256 fused with global load ----
#pragma unroll
  for (int q = 0; q < 16; ++q)
    a[q] = (v2f){x0[t + 256 * q], x1[t + 256 * q]};
  fft16(a);
  tw_pow16<false>(a, twg[t]);
#pragma unroll
  for (int q = 0; q < 16; ++q) d[PAD(t + 256 * q)] = a[q];
  __syncthreads();  // block-wide exchange (writers span the whole block)

  // ---- F16 ----
  const int b16 = (t >> 4) * 256 + (t & 15);
#pragma unroll
  for (int q = 0; q < 16; ++q) a[q] = d[PAD(b16 + 16 * q)];
  fft16(a);
  tw_pow16<false>(a, twg[(t & 15) * 16]);
#pragma unroll
  for (int q = 0; q < 16; ++q) d[PAD(b16 + 16 * q)] = a[q];
  // F16 -> F1: positions 16t+q are written by threads in t's own aligned
  // 16-thread group (same wave64) -> wave-local fence suffices.
  WAVE_FENCE();

  // ---- fused F1 + pointwise(CgT, pre-scaled 1/N) + I1 ----
#pragma unroll
  for (int q = 0; q < 16; ++q) a[q] = d[PAD(16 * t + q)];
  fft16(a);
#pragma unroll
  for (int q = 0; q < 16; ++q) a[q] = cmul(a[q], CgT[q * 256 + t]);
  ifft16(a);
#pragma unroll
  for (int q = 0; q < 16; ++q) d[PAD(16 * t + q)] = a[q];
  // I1 -> I16: same intra-wave group proof, roles swapped.
  WAVE_FENCE();

  // ---- I16: un-twiddle (conj) then inverse butterfly ----
#pragma unroll
  for (int q = 0; q < 16; ++q) a[q] = d[PAD(b16 + 16 * q)];
  tw_pow16<true>(a, twg[(t & 15) * 16]);
  ifft16(a);
#pragma unroll
  for (int q = 0; q < 16; ++q) d[PAD(b16 + 16 * q)] = a[q];
  __syncthreads();  // block-wide exchange (I256 readers span the block)

  // ---- I256 fused with global store + bias ----
#pragma unroll
  for (int q = 0; q < 16; ++q) a[q] = d[PAD(t + 256 * q)];
  tw_pow16<true>(a, twg[t]);
  ifft16(a);
#pragma unroll
  for (int q = 0; q < 16; ++q) {
    const int idx = t + 256 * q;
    const float bv = bias[idx];
    y0[idx] = a[q].x + bv;
    y1[idx] = a[q].y + bv;
  }
}

// ---------------- fallback GEMM (no ws / odd shapes) ----------------

typedef __attribute__((ext_vector_type(8))) short bf16x8;

__device__ __forceinline__ unsigned short f2bf(float f) {
  union { __hip_bfloat16 h; unsigned short u; } v;
  v.h = __float2bfloat16(f);
  return v.u;
}

#define LDP 72

__global__ __launch_bounds__(256) void circ_gemm_fb(
    const float* __restrict__ x, const float* __restrict__ r,
    const float* __restrict__ bias, float* __restrict__ y, int n) {
  __shared__ unsigned short Asf[128][LDP];
  __shared__ unsigned short Bsf[128][LDP];

  const int tid = threadIdx.x;
  const int wid = tid >> 6;
  const int lane = tid & 63;
  const int bm0 = blockIdx.y * 128;
  const int bn0 = blockIdx.x * 128;
  const int m0w = (wid >> 1) * 64;
  const int n0w = (wid & 1) * 64;
  const int lr = lane & 15;
  const int lk = (lane >> 4) * 8;
  const int mask = n - 1;

  f32x4 acc[4][4];
#pragma unroll
  for (int i = 0; i < 4; ++i)
#pragma unroll
    for (int j = 0; j < 4; ++j) acc[i][j] = (f32x4){0.f, 0.f, 0.f, 0.f};

  const int arow = tid >> 4;
  const int acol = (tid & 15) * 4;
  const int bnn = tid >> 1;
  const int bk0 = (tid & 1) * 32;

  for (int k0 = 0; k0 < n; k0 += 64) {
#pragma unroll
    for (int p = 0; p < 8; ++p) {
      const float4 v =
          *(const float4*)&x[(size_t)(bm0 + arow + p * 16) * n + k0 + acol];
      us4 hh;
      hh.x = f2bf(v.x); hh.y = f2bf(v.y); hh.z = f2bf(v.z); hh.w = f2bf(v.w);
      *(us4*)&Asf[arow + p * 16][acol] = hh;
    }
    {
      const int base = k0 + bk0 - bn0 - bnn;
#pragma unroll
      for (int kq = 0; kq < 32; kq += 4) {
        us4 hh;
        hh.x = f2bf(r[(base + kq + 0) & mask]);
        hh.y = f2bf(r[(base + kq + 1) & mask]);
        hh.z = f2bf(r[(base + kq + 2) & mask]);
        hh.w = f2bf(r[(base + kq + 3) & mask]);
        *(us4*)&Bsf[bnn][bk0 + kq] = hh;
      }
    }
    __syncthreads();

#pragma unroll
    for (int kk = 0; kk < 2; ++kk) {
      bf16x8 af[4], bfr[4];
#pragma unroll
      for (int mi = 0; mi < 4; ++mi)
        af[mi] = *(const bf16x8*)&Asf[m0w + mi * 16 + lr][kk * 32 + lk];
#pragma unroll
      for (int ni = 0; ni < 4; ++ni)
        bfr[ni] = *(const bf16x8*)&Bsf[n0w + ni * 16 + lr][kk * 32 + lk];
#pragma unroll
      for (int mi = 0; mi < 4; ++mi)
#pragma unroll
        for (int ni = 0; ni < 4; ++ni)
          acc[mi][ni] = __builtin_amdgcn_mfma_f32_16x16x32_bf16(
              af[mi], bfr[ni], acc[mi][ni], 0, 0, 0);
    }
    __syncthreads();
  }

#pragma unroll
  for (int ni = 0; ni < 4; ++ni) {
    const int col = bn0 + n0w + ni * 16 + lr;
    const float bv = bias[col];
#pragma unroll
    for (int mi = 0; mi < 4; ++mi) {
      const int row0 = bm0 + m0w + mi * 16 + (lane >> 4) * 4;
#pragma unroll
      for (int j = 0; j < 4; ++j)
        y[(size_t)(row0 + j) * n + col] = acc[mi][ni][j] + bv;
    }
  }
}

// ---------------- launch ----------------

extern "C" void kernel_launch(void* const* d_in, const int* in_sizes, int n_in,
                              void* d_out, int out_size, void* d_ws,
                              size_t ws_size, hipStream_t stream) {
  const float* x = (const float*)d_in[0];
  const float* r = (const float*)d_in[1];
  const float* b = (const float*)d_in[2];
  float* y = (float*)d_out;
  const int n = in_sizes[1];          // 4096
  const int batch = in_sizes[0] / n;  // 8192

  if (n == NFFT && (batch & 1) == 0 && ws_size >= 2 * NFFT * sizeof(v2f)) {
    v2f* twg = (v2f*)d_ws;
    v2f* CgT = twg + NFFT;
    build_tw<<<NFFT / 256, 256, 0, stream>>>(twg);
    build_C<<<1, 256, 0, stream>>>(r, twg, CgT);
    fft_conv15<<<batch / 2, 256, 0, stream>>>(x, CgT, twg, b, y);
  } else {
    dim3 grid(n / 128, batch / 128);
    circ_gemm_fb<<<grid, 256, 0, stream>>>(x, r, b, y, n);
  }
}

// Round 23
// 63.278 us; speedup vs baseline: 1.4235x; 1.4235x over previous
//
#include <hip/hip_runtime.h>
#include <hip/hip_bf16.h>
#include <math.h>

// y[b,i] = sum_j x[b,j] * r[(j-i) mod N] + bias[i]
//        = circular conv: y = IFFT(FFT(x) * FFT(c)) + bias, c[k] = r[(-k) mod N]
// Radix-16 FFT (N=4096 = 16^3), fp32, in-LDS, two rows packed per FFT.
//   FINAL CONFIG (R16/R21, ~63 us): 3 fwd + 3 inv stages; outer stages fused
//   with DIRECT global I/O; 5 stage-passes, 8 LDS touches/elem, 4 barriers;
//   VOP3P pk-asm complex math; tree twiddle powers; 1/N folded into CgT;
//   PAD(i)=i+(i>>4); launch_bounds(256,2).
//   Refuted variants: R17 fence+pins (-17%), R18 swizzle+5blk spill (-75%),
//   R19 swizzle-only (-5%), R20 ILP-2 (-22%), R22 bare fence (-43%).

#define NFFT 4096
#define PAD(i) ((i) + ((i) >> 4))

typedef __attribute__((ext_vector_type(2))) float v2f;
typedef __attribute__((ext_vector_type(4))) float f32x4;
typedef __attribute__((ext_vector_type(4))) unsigned short us4;

#define RQ 0.70710678118654752f
#define C1 0.9238795325112867f
#define S1 0.3826834323650898f

// ---- VOP3P packed-fp32 primitives (HW-verified R14/R15/R16) ----
__device__ __forceinline__ v2f padd(v2f a, v2f b) {
  v2f r;
  asm("v_pk_add_f32 %0, %1, %2" : "=v"(r) : "v"(a), "v"(b));
  return r;
}
__device__ __forceinline__ v2f psub(v2f a, v2f b) {
  v2f r;
  asm("v_pk_add_f32 %0, %1, %2 neg_lo:[0,1] neg_hi:[0,1]"
      : "=v"(r) : "v"(a), "v"(b));
  return r;
}
// a + (-i)*b = {a.x + b.y, a.y - b.x}
__device__ __forceinline__ v2f addmni(v2f a, v2f b) {
  v2f r;
  asm("v_pk_add_f32 %0, %1, %2 op_sel:[0,1] op_sel_hi:[1,0] neg_hi:[0,1]"
      : "=v"(r) : "v"(a), "v"(b));
  return r;
}
// a + (+i)*b = {a.x - b.y, a.y + b.x}
__device__ __forceinline__ v2f addmpi(v2f a, v2f b) {
  v2f r;
  asm("v_pk_add_f32 %0, %1, %2 op_sel:[0,1] op_sel_hi:[1,0] neg_lo:[0,1]"
      : "=v"(r) : "v"(a), "v"(b));
  return r;
}
// complex a*b
__device__ __forceinline__ v2f cmul(v2f a, v2f b) {
  v2f t, r;
  asm("v_pk_mul_f32 %0, %1, %2 op_sel:[0,0] op_sel_hi:[0,1]"
      : "=v"(t) : "v"(a), "v"(b));
  asm("v_pk_fma_f32 %0, %1, %2, %3 op_sel:[1,1,0] op_sel_hi:[1,0,1] neg_lo:[1,0,0]"
      : "=v"(r) : "v"(a), "v"(b), "v"(t));
  return r;
}
// complex a*conj(b)
__device__ __forceinline__ v2f cmulj(v2f a, v2f b) {
  v2f t, r;
  asm("v_pk_mul_f32 %0, %1, %2 op_sel:[0,0] op_sel_hi:[1,0]"
      : "=v"(t) : "v"(a), "v"(b));
  asm("v_pk_fma_f32 %0, %1, %2, %3 op_sel:[1,1,0] op_sel_hi:[0,1,1] neg_hi:[1,0,0]"
      : "=v"(r) : "v"(a), "v"(b), "v"(t));
  return r;
}

// ---- 4-point DFT building blocks (in-place, by reference) ----
__device__ __forceinline__ void fft4(v2f& x0, v2f& x1, v2f& x2, v2f& x3) {
  v2f t0 = padd(x0, x2), t1 = psub(x0, x2);
  v2f t2 = padd(x1, x3), t3 = psub(x1, x3);
  x0 = padd(t0, t2); x1 = addmni(t1, t3);
  x2 = psub(t0, t2); x3 = addmpi(t1, t3);
}
__device__ __forceinline__ void ifft4(v2f& x0, v2f& x1, v2f& x2, v2f& x3) {
  v2f t0 = padd(x0, x2), t1 = psub(x0, x2);
  v2f t2 = padd(x1, x3), t3 = psub(x1, x3);
  x0 = padd(t0, t2); x1 = addmpi(t1, t3);
  x2 = psub(t0, t2); x3 = addmni(t1, t3);
}

// ---- natural-order 16-point DFT (HW-verified R16) ----
__device__ __forceinline__ void fft16(v2f a[16]) {
  fft4(a[0], a[4], a[8], a[12]);
  fft4(a[1], a[5], a[9], a[13]);
  fft4(a[2], a[6], a[10], a[14]);
  fft4(a[3], a[7], a[11], a[15]);
  const v2f W1 = {C1, -S1}, W2 = {RQ, -RQ}, W3 = {S1, -C1};
  const v2f W6 = {-RQ, -RQ}, W9 = {-C1, S1};
  a[5] = cmul(a[5], W1);  a[9] = cmul(a[9], W2);   a[13] = cmul(a[13], W3);
  a[6] = cmul(a[6], W2);  /* a[10]: *(-i) folded */ a[14] = cmul(a[14], W6);
  a[7] = cmul(a[7], W3);  a[11] = cmul(a[11], W6); a[15] = cmul(a[15], W9);
  v2f x[16];
  {
    v2f t0 = padd(a[0], a[2]), t1 = psub(a[0], a[2]);
    v2f t2 = padd(a[1], a[3]), t3 = psub(a[1], a[3]);
    x[0] = padd(t0, t2); x[4] = addmni(t1, t3);
    x[8] = psub(t0, t2); x[12] = addmpi(t1, t3);
  }
  {
    v2f t0 = padd(a[4], a[6]), t1 = psub(a[4], a[6]);
    v2f t2 = padd(a[5], a[7]), t3 = psub(a[5], a[7]);
    x[1] = padd(t0, t2); x[5] = addmni(t1, t3);
    x[9] = psub(t0, t2); x[13] = addmpi(t1, t3);
  }
  {
    v2f t0 = addmni(a[8], a[10]), t1 = addmpi(a[8], a[10]);
    v2f t2 = padd(a[9], a[11]), t3 = psub(a[9], a[11]);
    x[2] = padd(t0, t2); x[6] = addmni(t1, t3);
    x[10] = psub(t0, t2); x[14] = addmpi(t1, t3);
  }
  {
    v2f t0 = padd(a[12], a[14]), t1 = psub(a[12], a[14]);
    v2f t2 = padd(a[13], a[15]), t3 = psub(a[13], a[15]);
    x[3] = padd(t0, t2); x[7] = addmni(t1, t3);
    x[11] = psub(t0, t2); x[15] = addmpi(t1, t3);
  }
#pragma unroll
  for (int q = 0; q < 16; ++q) a[q] = x[q];
}

__device__ __forceinline__ void ifft16(v2f a[16]) {
  ifft4(a[0], a[4], a[8], a[12]);
  ifft4(a[1], a[5], a[9], a[13]);
  ifft4(a[2], a[6], a[10], a[14]);
  ifft4(a[3], a[7], a[11], a[15]);
  const v2f W1 = {C1, -S1}, W2 = {RQ, -RQ}, W3 = {S1, -C1};
  const v2f W6 = {-RQ, -RQ}, W9 = {-C1, S1};
  a[5] = cmulj(a[5], W1);  a[9] = cmulj(a[9], W2);   a[13] = cmulj(a[13], W3);
  a[6] = cmulj(a[6], W2);  /* a[10]: *(+i) folded */  a[14] = cmulj(a[14], W6);
  a[7] = cmulj(a[7], W3);  a[11] = cmulj(a[11], W6); a[15] = cmulj(a[15], W9);
  v2f x[16];
  {
    v2f t0 = padd(a[0], a[2]), t1 = psub(a[0], a[2]);
    v2f t2 = padd(a[1], a[3]), t3 = psub(a[1], a[3]);
    x[0] = padd(t0, t2); x[4] = addmpi(t1, t3);
    x[8] = psub(t0, t2); x[12] = addmni(t1, t3);
  }
  {
    v2f t0 = padd(a[4], a[6]), t1 = psub(a[4], a[6]);
    v2f t2 = padd(a[5], a[7]), t3 = psub(a[5], a[7]);
    x[1] = padd(t0, t2); x[5] = addmpi(t1, t3);
    x[9] = psub(t0, t2); x[13] = addmni(t1, t3);
  }
  {
    v2f t0 = addmpi(a[8], a[10]), t1 = addmni(a[8], a[10]);
    v2f t2 = padd(a[9], a[11]), t3 = psub(a[9], a[11]);
    x[2] = padd(t0, t2); x[6] = addmpi(t1, t3);
    x[10] = psub(t0, t2); x[14] = addmni(t1, t3);
  }
  {
    v2f t0 = padd(a[12], a[14]), t1 = psub(a[12], a[14]);
    v2f t2 = padd(a[13], a[15]), t3 = psub(a[13], a[15]);
    x[3] = padd(t0, t2); x[7] = addmpi(t1, t3);
    x[11] = psub(t0, t2); x[15] = addmni(t1, t3);
  }
#pragma unroll
  for (int q = 0; q < 16; ++q) a[q] = x[q];
}

// apply a[q] *= b^q (CONJ: *= conj(b^q)); tree powers
template <bool CONJ>
__device__ __forceinline__ void tw_pow16(v2f a[16], v2f b) {
  const v2f p2 = cmul(b, b);
  const v2f p3 = cmul(p2, b);
  const v2f p4 = cmul(p2, p2);
  const v2f p5 = cmul(p4, b);
  const v2f p6 = cmul(p4, p2);
  const v2f p7 = cmul(p4, p3);
  const v2f p8 = cmul(p4, p4);
#define APQ(q, p)                         \
  if constexpr (CONJ) a[q] = cmulj(a[q], p); \
  else a[q] = cmul(a[q], p)
  APQ(1, b); APQ(2, p2); APQ(3, p3); APQ(4, p4);
  APQ(5, p5); APQ(6, p6); APQ(7, p7); APQ(8, p8);
  APQ(9, cmul(p8, b)); APQ(10, cmul(p8, p2)); APQ(11, cmul(p8, p3));
  APQ(12, cmul(p8, p4)); APQ(13, cmul(p8, p5)); APQ(14, cmul(p8, p6));
  APQ(15, cmul(p8, p7));
#undef APQ
}

// ---------------- kernel 0: twiddle table tw[j] = e^{-2pi i j/N} ----------------
__global__ __launch_bounds__(256) void build_tw(v2f* __restrict__ twg) {
  const int j = blockIdx.x * 256 + threadIdx.x;
  if (j < NFFT) {
    double ang = (-2.0 * 3.14159265358979323846) * (double)j / (double)NFFT;
    twg[j] = (v2f){(float)cos(ang), (float)sin(ang)};
  }
}

// ---- kernel 1: CgT[q*256+t] = (fwd chain of c at slot q of thread t)/N ----
__global__ __launch_bounds__(256, 2) void build_C(const float* __restrict__ r,
                                                  const v2f* __restrict__ twg,
                                                  v2f* __restrict__ CgT) {
  __shared__ v2f d[PAD(NFFT - 1) + 1];
  const int t = threadIdx.x;
  v2f a[16];
#pragma unroll
  for (int q = 0; q < 16; ++q) {
    const int idx = t + 256 * q;
    a[q] = (v2f){r[(NFFT - idx) & (NFFT - 1)], 0.f};
  }
  fft16(a);
  tw_pow16<false>(a, twg[t]);
#pragma unroll
  for (int q = 0; q < 16; ++q) d[PAD(t + 256 * q)] = a[q];
  __syncthreads();
  const int b16 = (t >> 4) * 256 + (t & 15);
#pragma unroll
  for (int q = 0; q < 16; ++q) a[q] = d[PAD(b16 + 16 * q)];
  fft16(a);
  tw_pow16<false>(a, twg[(t & 15) * 16]);
#pragma unroll
  for (int q = 0; q < 16; ++q) d[PAD(b16 + 16 * q)] = a[q];
  __syncthreads();
#pragma unroll
  for (int q = 0; q < 16; ++q) a[q] = d[PAD(16 * t + q)];
  fft16(a);
  const float s = 1.0f / (float)NFFT;
#pragma unroll
  for (int q = 0; q < 16; ++q)
    CgT[q * 256 + t] = (v2f){a[q].x * s, a[q].y * s};
}

// ------ kernel 2: packed 2-row radix-16 FFT conv, direct-global ends ------
__global__ __launch_bounds__(256, 2) void fft_conv10(
    const float* __restrict__ x, const v2f* __restrict__ CgT,
    const v2f* __restrict__ twg, const float* __restrict__ bias,
    float* __restrict__ y) {
  __shared__ v2f d[PAD(NFFT - 1) + 1];
  const int t = threadIdx.x;  // 0..255
  const size_t r0 = 2 * (size_t)blockIdx.x;
  const float* x0 = x + r0 * NFFT;
  const float* x1 = x0 + NFFT;
  float* y0 = y + r0 * NFFT;
  float* y1 = y0 + NFFT;

  v2f a[16];

  // ---- F256 fused with global load (scalar coalesced, verified R15) ----
#pragma unroll
  for (int q = 0; q < 16; ++q)
    a[q] = (v2f){x0[t + 256 * q], x1[t + 256 * q]};
  fft16(a);
  tw_pow16<false>(a, twg[t]);
#pragma unroll
  for (int q = 0; q < 16; ++q) d[PAD(t + 256 * q)] = a[q];
  __syncthreads();

  // ---- F16 ----
  const int b16 = (t >> 4) * 256 + (t & 15);
#pragma unroll
  for (int q = 0; q < 16; ++q) a[q] = d[PAD(b16 + 16 * q)];
  fft16(a);
  tw_pow16<false>(a, twg[(t & 15) * 16]);
#pragma unroll
  for (int q = 0; q < 16; ++q) d[PAD(b16 + 16 * q)] = a[q];
  __syncthreads();

  // ---- fused F1 + pointwise(CgT, pre-scaled 1/N) + I1 ----
#pragma unroll
  for (int q = 0; q < 16; ++q) a[q] = d[PAD(16 * t + q)];
  fft16(a);
#pragma unroll
  for (int q = 0; q < 16; ++q) a[q] = cmul(a[q], CgT[q * 256 + t]);
  ifft16(a);
#pragma unroll
  for (int q = 0; q < 16; ++q) d[PAD(16 * t + q)] = a[q];
  __syncthreads();

  // ---- I16: un-twiddle (conj) then inverse butterfly ----
#pragma unroll
  for (int q = 0; q < 16; ++q) a[q] = d[PAD(b16 + 16 * q)];
  tw_pow16<true>(a, twg[(t & 15) * 16]);
  ifft16(a);
#pragma unroll
  for (int q = 0; q < 16; ++q) d[PAD(b16 + 16 * q)] = a[q];
  __syncthreads();

  // ---- I256 fused with global store + bias ----
#pragma unroll
  for (int q = 0; q < 16; ++q) a[q] = d[PAD(t + 256 * q)];
  tw_pow16<true>(a, twg[t]);
  ifft16(a);
#pragma unroll
  for (int q = 0; q < 16; ++q) {
    const int idx = t + 256 * q;
    const float bv = bias[idx];
    y0[idx] = a[q].x + bv;
    y1[idx] = a[q].y + bv;
  }
}

// ---------------- fallback GEMM (no ws / odd shapes) ----------------

typedef __attribute__((ext_vector_type(8))) short bf16x8;

__device__ __forceinline__ unsigned short f2bf(float f) {
  union { __hip_bfloat16 h; unsigned short u; } v;
  v.h = __float2bfloat16(f);
  return v.u;
}

#define LDP 72

__global__ __launch_bounds__(256) void circ_gemm_fb(
    const float* __restrict__ x, const float* __restrict__ r,
    const float* __restrict__ bias, float* __restrict__ y, int n) {
  __shared__ unsigned short Asf[128][LDP];
  __shared__ unsigned short Bsf[128][LDP];

  const int tid = threadIdx.x;
  const int wid = tid >> 6;
  const int lane = tid & 63;
  const int bm0 = blockIdx.y * 128;
  const int bn0 = blockIdx.x * 128;
  const int m0w = (wid >> 1) * 64;
  const int n0w = (wid & 1) * 64;
  const int lr = lane & 15;
  const int lk = (lane >> 4) * 8;
  const int mask = n - 1;

  f32x4 acc[4][4];
#pragma unroll
  for (int i = 0; i < 4; ++i)
#pragma unroll
    for (int j = 0; j < 4; ++j) acc[i][j] = (f32x4){0.f, 0.f, 0.f, 0.f};

  const int arow = tid >> 4;
  const int acol = (tid & 15) * 4;
  const int bnn = tid >> 1;
  const int bk0 = (tid & 1) * 32;

  for (int k0 = 0; k0 < n; k0 += 64) {
#pragma unroll
    for (int p = 0; p < 8; ++p) {
      const float4 v =
          *(const float4*)&x[(size_t)(bm0 + arow + p * 16) * n + k0 + acol];
      us4 hh;
      hh.x = f2bf(v.x); hh.y = f2bf(v.y); hh.z = f2bf(v.z); hh.w = f2bf(v.w);
      *(us4*)&Asf[arow + p * 16][acol] = hh;
    }
    {
      const int base = k0 + bk0 - bn0 - bnn;
#pragma unroll
      for (int kq = 0; kq < 32; kq += 4) {
        us4 hh;
        hh.x = f2bf(r[(base + kq + 0) & mask]);
        hh.y = f2bf(r[(base + kq + 1) & mask]);
        hh.z = f2bf(r[(base + kq + 2) & mask]);
        hh.w = f2bf(r[(base + kq + 3) & mask]);
        *(us4*)&Bsf[bnn][bk0 + kq] = hh;
      }
    }
    __syncthreads();

#pragma unroll
    for (int kk = 0; kk < 2; ++kk) {
      bf16x8 af[4], bfr[4];
#pragma unroll
      for (int mi = 0; mi < 4; ++mi)
        af[mi] = *(const bf16x8*)&Asf[m0w + mi * 16 + lr][kk * 32 + lk];
#pragma unroll
      for (int ni = 0; ni < 4; ++ni)
        bfr[ni] = *(const bf16x8*)&Bsf[n0w + ni * 16 + lr][kk * 32 + lk];
#pragma unroll
      for (int mi = 0; mi < 4; ++mi)
#pragma unroll
        for (int ni = 0; ni < 4; ++ni)
          acc[mi][ni] = __builtin_amdgcn_mfma_f32_16x16x32_bf16(
              af[mi], bfr[ni], acc[mi][ni], 0, 0, 0);
    }
    __syncthreads();
  }

#pragma unroll
  for (int ni = 0; ni < 4; ++ni) {
    const int col = bn0 + n0w + ni * 16 + lr;
    const float bv = bias[col];
#pragma unroll
    for (int mi = 0; mi < 4; ++mi) {
      const int row0 = bm0 + m0w + mi * 16 + (lane >> 4) * 4;
#pragma unroll
      for (int j = 0; j < 4; ++j)
        y[(size_t)(row0 + j) * n + col] = acc[mi][ni][j] + bv;
    }
  }
}

// ---------------- launch ----------------

extern "C" void kernel_launch(void* const* d_in, const int* in_sizes, int n_in,
                              void* d_out, int out_size, void* d_ws,
                              size_t ws_size, hipStream_t stream) {
  const float* x = (const float*)d_in[0];
  const float* r = (const float*)d_in[1];
  const float* b = (const float*)d_in[2];
  float* y = (float*)d_out;
  const int n = in_sizes[1];          // 4096
  const int batch = in_sizes[0] / n;  // 8192

  if (n == NFFT && (batch & 1) == 0 && ws_size >= 2 * NFFT * sizeof(v2f)) {
    v2f* twg = (v2f*)d_ws;
    v2f* CgT = twg + NFFT;
    build_tw<<<NFFT / 256, 256, 0, stream>>>(twg);
    build_C<<<1, 256, 0, stream>>>(r, twg, CgT);
    fft_conv10<<<batch / 2, 256, 0, stream>>>(x, CgT, twg, b, y);
  } else {
    dim3 grid(n / 128, batch / 128);
    circ_gemm_fb<<<grid, 256, 0, stream>>>(x, r, b, y, n);
  }
}